// Round 2
// 329.780 us; speedup vs baseline: 1.0422x; 1.0422x over previous
//
#include <hip/hip_runtime.h>

typedef unsigned short u16;
typedef unsigned int u32;
typedef float __attribute__((ext_vector_type(4))) f32x4;

#define BB 256
#define NN 196
#define DD 768
#define PP 32
#define TOPK 5
#define NROW 216           /* 20 + 196 */

/* fp32 element offsets in d_out (flat concat in return order) */
#define OUT0_ELTS (BB * NROW * DD)   /* 42467328 */
#define RS_OFF    OUT0_ELTS
#define SIM_OFF   (OUT0_ELTS + 1)
#define IDX_OFF   (OUT0_ELTS + 1 + BB * PP)

/* ws layout (byte offsets) */
#define WS_PNORM  0                          /* 32*768  fp32 =  98304 B */
#define WS_PEMB   98304                      /* 128*768 fp32 = 393216 B */
#define WS_IDX    491520                     /* 256*5 int    =   5120 B */

/* ---- Kernel 1 (merged): blocks 0..31 l2-normalize prompt_key;
   blocks 32..127 patch-embed (4 positions x 256 channels per block,
   patches staged in LDS -> each cw float4 reused 4x in registers). */
__global__ __launch_bounds__(256) void k_prep(const float* __restrict__ pkey,
                                              const float* __restrict__ prompt,
                                              const float* __restrict__ cw,
                                              const float* __restrict__ cb,
                                              float* __restrict__ pnorm,
                                              float* __restrict__ pemb) {
    const int t = threadIdx.x;
    if (blockIdx.x < PP) {
        /* ---- prompt_key L2 normalize ---- */
        const int p = blockIdx.x;
        const float* row = pkey + (size_t)p * DD;
        float v0 = row[t], v1 = row[t + 256], v2 = row[t + 512];
        float sq = v0 * v0 + v1 * v1 + v2 * v2;
#pragma unroll
        for (int off = 32; off; off >>= 1) sq += __shfl_down(sq, off);
        __shared__ float wsum[4];
        __shared__ float rshared;
        if ((t & 63) == 0) wsum[t >> 6] = sq;
        __syncthreads();
        if (t == 0) rshared = rsqrtf(fmaxf(wsum[0] + wsum[1] + wsum[2] + wsum[3], 1e-12f));
        __syncthreads();
        float r = rshared;
        float* orow = pnorm + (size_t)p * DD;
        orow[t] = v0 * r;
        orow[t + 256] = v1 * r;
        orow[t + 512] = v2 * r;
    } else {
        /* ---- patch embed: 4 positions x 256 channels per block ---- */
        const int bxx = blockIdx.x - PP;            /* 0..95 */
        const int chunk = bxx / 32, pg = bxx - chunk * 32;
        const int m0 = pg * 4;                      /* 4 positions m0..m0+3 */
        const int n = chunk * 256 + t;              /* output channel */
        __shared__ float patch[4 * DD];
        for (int idx = t; idx < 4 * DD; idx += 256) {
            const int j = idx / DD, kk = idx - j * DD;
            const int c = kk >> 8, rem = kk & 255;
            const int kh = rem >> 4, kw = rem & 15;
            const int m = m0 + j;
            const int p = m >> 2, l = m & 3;
            patch[idx] = prompt[(size_t)p * 3072 + (size_t)c * 1024
                                + ((l >> 1) * 16 + kh) * 32 + (l & 1) * 16 + kw];
        }
        __syncthreads();
        const float4* wrow = (const float4*)(cw + (size_t)n * DD);
        const float4* p0 = (const float4*)(patch);
        const float4* p1 = (const float4*)(patch + DD);
        const float4* p2 = (const float4*)(patch + 2 * DD);
        const float4* p3 = (const float4*)(patch + 3 * DD);
        float a0 = 0.f, a1 = 0.f, a2 = 0.f, a3 = 0.f;
#pragma unroll 4
        for (int kk = 0; kk < 192; ++kk) {
            const float4 w = wrow[kk];
            const float4 q0 = p0[kk], q1 = p1[kk], q2 = p2[kk], q3 = p3[kk];
            a0 += q0.x * w.x + q0.y * w.y + q0.z * w.z + q0.w * w.w;
            a1 += q1.x * w.x + q1.y * w.y + q1.z * w.z + q1.w * w.w;
            a2 += q2.x * w.x + q2.y * w.y + q2.z * w.z + q2.w * w.w;
            a3 += q3.x * w.x + q3.y * w.y + q3.z * w.z + q3.w * w.w;
        }
        const float bias = cb[n];
        pemb[(size_t)(m0 + 0) * DD + n] = a0 + bias;
        pemb[(size_t)(m0 + 1) * DD + n] = a1 + bias;
        pemb[(size_t)(m0 + 2) * DD + n] = a2 + bias;
        pemb[(size_t)(m0 + 3) * DD + n] = a3 + bias;
    }
}

/* ---- Kernel 2 (fused, heavy): per batch b — copy 196 x-rows into
   out0[20..216) with batched nontemporal loads/stores (7 in flight),
   column mean, L2-normalize, 32 dots, wave-parallel top-5, sim/idx
   writes, then gather 20 prompt-embed rows into out0[0..20). */
__global__ __launch_bounds__(768) void k_fused(const float* __restrict__ x,
                                               const float* __restrict__ pnorm,
                                               const float* __restrict__ pemb,
                                               float* __restrict__ out,
                                               int* __restrict__ idx_ws) {
    const int b = blockIdx.x;
    const int t = threadIdx.x;
    const int g = t / 192, c = t - g * 192;       /* c: float4-column 0..191 */
    const float* xb = x + (size_t)b * (NN * DD);
    float* ob = out + (size_t)b * (NROW * DD) + 20 * DD;
    f32x4 s = (f32x4)(0.f);
    /* 49 rows per thread group, batched 7x7: 7 NT loads in flight, then
       7 accumulate+NT stores. x and out0 are touch-once streams -> NT
       keeps them out of L2/L3. */
#pragma unroll
    for (int o = 0; o < 7; ++o) {
        f32x4 vv[7];
#pragma unroll
        for (int i = 0; i < 7; ++i) {
            const int row = g + 4 * (o * 7 + i);
            vv[i] = __builtin_nontemporal_load((const f32x4*)(xb + (size_t)row * DD) + c);
        }
#pragma unroll
        for (int i = 0; i < 7; ++i) {
            const int row = g + 4 * (o * 7 + i);
            s += vv[i];
            __builtin_nontemporal_store(vv[i], (f32x4*)(ob + (size_t)row * DD) + c);
        }
    }
    __shared__ f32x4 comb[768];
    __shared__ float xm[768];
    __shared__ float sims[PP];
    __shared__ float wred[12];
    __shared__ float rsh;
    __shared__ int lidx[TOPK];
    comb[g * 192 + c] = s;
    __syncthreads();
    if (g == 0) {
        f32x4 s0 = comb[c], s1 = comb[192 + c], s2 = comb[384 + c], s3 = comb[576 + c];
        const float inv = 1.0f / NN;
        f32x4 m4 = (s0 + s1 + s2 + s3) * inv;
        xm[4 * c + 0] = m4.x;
        xm[4 * c + 1] = m4.y;
        xm[4 * c + 2] = m4.z;
        xm[4 * c + 3] = m4.w;
    }
    __syncthreads();
    float sq = xm[t] * xm[t];
#pragma unroll
    for (int off = 32; off; off >>= 1) sq += __shfl_down(sq, off);
    if ((t & 63) == 0) wred[t >> 6] = sq;
    __syncthreads();
    if (t == 0) {
        float tot = 0.f;
        for (int i = 0; i < 12; ++i) tot += wred[i];
        rsh = rsqrtf(fmaxf(tot, 1e-12f));
    }
    __syncthreads();
    const float r = rsh;
    if (t < 512) {                                 /* 16 threads per prompt */
        const int p = t >> 4, sub = t & 15;
        const float* pr = pnorm + (size_t)p * DD;
        float acc = 0.f;
#pragma unroll 8
        for (int j = 0; j < 48; ++j) {
            const int k = sub + (j << 4);
            acc += xm[k] * pr[k];
        }
        acc += __shfl_down(acc, 8, 16);
        acc += __shfl_down(acc, 4, 16);
        acc += __shfl_down(acc, 2, 16);
        acc += __shfl_down(acc, 1, 16);
        if (sub == 0) {
            const float sv = acc * r;
            sims[p] = sv;
            out[SIM_OFF + b * PP + p] = sv;
        }
    }
    __syncthreads();
    /* wave-parallel top-5 on wave 0 (tie-break: lowest index, matching
       the serial scan / jax top_k stability) */
    if (t < 64) {
        float v = (t < PP) ? sims[t] : -1e30f;
#pragma unroll
        for (int k = 0; k < TOPK; ++k) {
            float bv = v; int bbi = t;
#pragma unroll
            for (int off = 32; off; off >>= 1) {
                const float ov = __shfl_xor(bv, off);
                const int   oi = __shfl_xor(bbi, off);
                if (ov > bv || (ov == bv && oi < bbi)) { bv = ov; bbi = oi; }
            }
            /* all 64 lanes agree on (bv, bbi) now */
            if (t == 0) {
                lidx[k] = bbi;
                idx_ws[b * TOPK + k] = bbi;
                out[IDX_OFF + b * TOPK + k] = (float)bbi;
            }
            if (t == bbi) v = -1e30f;
        }
    }
    __syncthreads();
    /* gather 20 prompt-embed rows (fp32, L2-resident) into out0[0..20) */
    f32x4* dst = (f32x4*)(out + (size_t)b * (NROW * DD));
    const f32x4* src = (const f32x4*)pemb;            /* 192 f32x4 per row */
    for (int v = t; v < 20 * 192; v += 768) {
        const int row = v / 192;
        const int off = v - row * 192;
        const int srow = lidx[row >> 2] * 4 + (row & 3);
        __builtin_nontemporal_store(src[srow * 192 + off], dst + row * 192 + off);
    }
}

/* ---- Kernel 3: reduce_sim = sum of top-5 sims over all b, / 256.
   Single block; deterministic (no atomics). */
__global__ __launch_bounds__(256) void k_final(const float* __restrict__ out_sim,
                                               const int* __restrict__ idx_ws,
                                               float* __restrict__ out_rs) {
    const int t = threadIdx.x;                       /* t = b */
    float s = 0.f;
#pragma unroll
    for (int k = 0; k < TOPK; ++k)
        s += out_sim[t * PP + idx_ws[t * TOPK + k]];
#pragma unroll
    for (int off = 32; off; off >>= 1) s += __shfl_down(s, off);
    __shared__ float wsum[4];
    if ((t & 63) == 0) wsum[t >> 6] = s;
    __syncthreads();
    if (t == 0) *out_rs = (wsum[0] + wsum[1] + wsum[2] + wsum[3]) * (1.0f / BB);
}

extern "C" void kernel_launch(void* const* d_in, const int* in_sizes, int n_in,
                              void* d_out, int out_size, void* d_ws, size_t ws_size,
                              hipStream_t stream) {
    const float* x      = (const float*)d_in[0];   /* x_embed   (256,196,768) fp32 */
    const float* prompt = (const float*)d_in[1];   /* prompt    (32,3,32,32)  fp32 */
    const float* pkey   = (const float*)d_in[2];   /* prompt_key(32,768)      fp32 */
    const float* cw     = (const float*)d_in[3];   /* conv_w    (768,3,16,16) fp32 */
    const float* cb     = (const float*)d_in[4];   /* conv_b    (768,)        fp32 */
    float* out = (float*)d_out;
    char* ws = (char*)d_ws;

    float* pnorm = (float*)(ws + WS_PNORM);
    float* pemb  = (float*)(ws + WS_PEMB);
    int*   idxw  = (int*)(ws + WS_IDX);

    k_prep<<<PP + 96, 256, 0, stream>>>(pkey, prompt, cw, cb, pnorm, pemb);
    k_fused<<<BB, 768, 0, stream>>>(x, pnorm, pemb, out, idxw);
    k_final<<<1, 256, 0, stream>>>(out + SIM_OFF, idxw, out + RS_OFF);
}